// Round 14
// baseline (970.236 us; speedup 1.0000x reference)
//
#include <hip/hip_runtime.h>
#include <hip/hip_bf16.h>

typedef unsigned short u16;
typedef __attribute__((ext_vector_type(8))) short short8;
typedef __attribute__((ext_vector_type(4))) float f32x4;

constexpr int SA     = 168;    // act row stride (bf16): 336 B
constexpr int BLK_E  = 64;     // edges per block
constexpr int NTHR   = 256;    // 4 waves = 2 M-groups x 2 N-groups (5/5 N-split)
constexpr int CHUNK  = 512;    // u16 elems per (ks,j) fragment chunk = 1 KB
constexpr int WSLOT  = 50 * CHUNK;              // 25600 elems per layer (5 ks x 10 j)
constexpr size_t WT_BYTES = 5ull * WSLOT * 2;   // 256000 B
constexpr size_t WS_HDR   = 262144;             // weights + padded bias

// slice schedule: s=0 -> (L0,ks0); s=1..15 -> L1..L3 (5 ks each); s=16..20 -> L4
constexpr int Ls (int s) { return s == 0 ? 0 : (s <= 15 ? 1 + (s - 1) / 5 : 4); }
constexpr int Kss(int s) { return s == 0 ? 0 : (s <= 15 ? (s - 1) % 5 : s - 16); }

__device__ __forceinline__ u16 f2bf(float f) {  // RNE (prep only)
    union { float f; unsigned u; } c; c.f = f;
    return (u16)((c.u + 0x7fffu + ((c.u >> 16) & 1u)) >> 16);
}
__device__ __forceinline__ unsigned pk_bf16(float a, float b) {  // v_cvt_pk_bf16_f32
    float2 f; f.x = a; f.y = b;
    __hip_bfloat162 h = __float22bfloat162_rn(f);
    return *(unsigned*)&h;
}

// act k'-storage (5/5 N-split):
//  tiles 0-3: k' = col*4 + j           (ng0 packed, b64)
//  tiles 5-8: k' = 64 + col*4 + (j-5)  (ng1 packed, b64)
//  tile  4 :  k' = 128 + col           (ng0 scalar)
//  tile  9 :  k' = 144 + col           (ng1 scalar)
__device__ __forceinline__ int kperm(int kp) {
    if (kp < 64)  return (kp & 3) * 16 + (kp >> 2);
    if (kp < 128) { const int m = kp - 64; return (5 + (m & 3)) * 16 + (m >> 2); }
    if (kp < 144) return 4 * 16 + (kp - 128);
    if (kp < 160) return 9 * 16 + (kp - 144);
    return 1 << 30;
}

// ---- prep: weights -> fragment-ordered chunks (+ padded bias at y==5) ------
__global__ void prep_all(const float* __restrict__ W0, const float* __restrict__ W1,
                         const float* __restrict__ W2, const float* __restrict__ W3,
                         const float* __restrict__ W4,
                         const float* __restrict__ B0, const float* __restrict__ B1,
                         const float* __restrict__ B2, const float* __restrict__ B3,
                         const float* __restrict__ B4,
                         u16* __restrict__ Wt, float* __restrict__ Bp)
{
    const int l = blockIdx.y;
    if (l == 5) {   // bias: 5 x 160, zero-padded
        const int idx = blockIdx.x * blockDim.x + threadIdx.x;
        if (idx < 800) {
            const int ll = idx / 160, j = idx - ll * 160;
            const float* B; int DO;
            if      (ll == 0) { B = B0; DO = 150; }
            else if (ll == 1) { B = B1; DO = 150; }
            else if (ll == 2) { B = B2; DO = 150; }
            else if (ll == 3) { B = B3; DO = 150; }
            else              { B = B4; DO = 50;  }
            Bp[idx] = (j < DO) ? B[j] : 0.f;
        }
        return;
    }
    const float* W; int DI, DO; bool perm;
    if      (l == 0) { W = W0; DI = 13;  DO = 150; perm = false; }
    else if (l == 1) { W = W1; DI = 150; DO = 150; perm = true;  }
    else if (l == 2) { W = W2; DI = 150; DO = 150; perm = true;  }
    else if (l == 3) { W = W3; DI = 150; DO = 150; perm = true;  }
    else             { W = W4; DI = 150; DO = 50;  perm = true;  }
    u16* dst = Wt + (size_t)l * WSLOT;
    for (int idx = blockIdx.x * blockDim.x + threadIdx.x; idx < WSLOT;
         idx += gridDim.x * blockDim.x) {
        const int chunk = idx / CHUNK;            // = ks*10 + j
        const int within = idx - chunk * CHUNK;
        const int lane = within >> 3, e = within & 7;
        const int ks = chunk / 10, j = chunk - ks * 10;
        const int c = lane & 15, q = lane >> 4;
        const int n = j * 16 + c;
        const int kphys = ks * 32 + q * 8 + e;
        const int klog = perm ? kperm(kphys) : kphys;
        const float v = (n < DO && klog < DI) ? W[klog * DO + n] : 0.f;
        dst[idx] = f2bf(v);
    }
}

// ---- B-load for slice s (plain global->VGPR, coalesced 1 KB chunks) --------
__device__ __forceinline__ void loadB(const u16* __restrict__ Wt, int s,
                                      int ng, int lane, short8 (&slot)[5])
{
    const int l = Ls(s), ks = Kss(s);
    const int jb = (l < 4) ? ng * 5 : 0;
    const int nt = (l < 4) ? 5 : 4;
    const u16* base = Wt + (size_t)l * WSLOT + (size_t)(ks * 10 + jb) * CHUNK + lane * 8;
#pragma unroll
    for (int jj = 0; jj < 5; ++jj)
        if (jj < nt) slot[jj] = *(const short8*)&base[jj * CHUNK];
}

// ---- epilogue: bias+relu, packed bf16, k'-permuted in-place store ----------
// wave (mg,ng): rows of its 2 M-tiles; cols ng's 5 tiles (4 packed b64 + 1 scalar)
__device__ __forceinline__ void epilogue(u16* act, const float* __restrict__ Bp,
                                         int l, int mg, int ng, int col, int quad,
                                         f32x4 (&acc)[2][5])
{
    float bb[5];
#pragma unroll
    for (int jj = 0; jj < 5; ++jj) bb[jj] = Bp[l * 160 + (ng * 5 + jj) * 16 + col];
#pragma unroll
    for (int mtl = 0; mtl < 2; ++mtl)
#pragma unroll
        for (int r = 0; r < 4; ++r) {
            u16* row = &act[((mg * 2 + mtl) * 16 + quad * 4 + r) * SA];
            uint2 pk;
            pk.x = pk_bf16(fmaxf(acc[mtl][0][r] + bb[0], 0.f),
                           fmaxf(acc[mtl][1][r] + bb[1], 0.f));
            pk.y = pk_bf16(fmaxf(acc[mtl][2][r] + bb[2], 0.f),
                           fmaxf(acc[mtl][3][r] + bb[3], 0.f));
            *(uint2*)&row[ng * 64 + col * 4] = pk;                 // tiles 0-3 / 5-8
            row[128 + ng * 16 + col] =                             // tile 4 / 9
                (u16)pk_bf16(fmaxf(acc[mtl][4][r] + bb[4], 0.f), 0.f);
        }
}

// ------------------------------- Edge kernel --------------------------------
// 4 waves = 2 M-groups (32 edges each) x 2 N-groups (5 N-tiles each).
// B: global->VGPR rolling 3-slice window. Sync: 1 post-gather + 2 per layer
// boundary = 9 barriers. ~125 regs/wave -> 4 waves/SIMD; LDS 21.8 KB ->
// 4 blocks x 4 waves = 16 waves/CU in 4 independent barrier groups.
__global__ __launch_bounds__(NTHR, 4) void edge_kernel(
    const float* __restrict__ t, const float* __restrict__ x, const float* __restrict__ Ofx,
    const int* __restrict__ src, const int* __restrict__ tgt,
    const u16* __restrict__ Wt, const float* __restrict__ Bp,
    float* __restrict__ Ep, int n_edges, int copy_mask, size_t copy_elems)
{
    __shared__ __align__(16) u16 act[BLK_E * SA];      // 21504 B
    __shared__ int tgt_s[BLK_E];                       // 256 B

    const int tid  = threadIdx.x;
    const int lane = tid & 63;
    const int wv   = tid >> 6;
    const int mg   = wv >> 1;          // M-group: edges [mg*32, mg*32+32)
    const int ng   = wv & 1;           // N-group: tiles [ng*5, ng*5+5)
    const int col  = lane & 15;
    const int quad = lane >> 4;

    const int xcd = (int)(__builtin_amdgcn_s_getreg(6164) & 7u) & copy_mask;
    float* __restrict__ Epc = Ep + (size_t)xcd * copy_elems;

    short8 Bwin[3][5];
    loadB(Wt, 0, ng, lane, Bwin[0]);    // prologue: 3-deep lookahead
    loadB(Wt, 1, ng, lane, Bwin[1]);
    loadB(Wt, 2, ng, lane, Bwin[2]);

    // ---- gather R' (tid<64; visible to all after first barrier) ----
    if (tid < BLK_E) {
        const int e = tid;
        const long long ge = (long long)blockIdx.x * BLK_E + e;
        const bool valid = ge < n_edges;
        const int s = valid ? src[ge] : 0;
        const int g = valid ? tgt[ge] : 0;
        const float4 xs = valid ? *(const float4*)&x[(size_t)s * 4] : float4{0, 0, 0, 0};
        const float2 os = valid ? *(const float2*)&Ofx[(size_t)s * 2] : float2{0, 0};
        const float4 xg = valid ? *(const float4*)&x[(size_t)g * 4] : float4{0, 0, 0, 0};
        const float2 og = valid ? *(const float2*)&Ofx[(size_t)g * 2] : float2{0, 0};
        const float tv = valid ? t[0] : 0.f;
        uint4 w0, w1;
        w0.x = pk_bf16(xs.x, xs.y); w0.y = pk_bf16(xs.z, xs.w);
        w0.z = pk_bf16(os.x, os.y); w0.w = pk_bf16(xg.x, xg.y);
        w1.x = pk_bf16(xg.z, xg.w); w1.y = pk_bf16(og.x, og.y);
        w1.z = pk_bf16(tv, 0.f);    w1.w = 0u;
        u16* row = &act[e * SA];
        *(uint4*)&row[0]  = w0;
        *(uint4*)&row[8]  = w1;
        *(uint4*)&row[16] = uint4{0, 0, 0, 0};
        *(uint4*)&row[24] = uint4{0, 0, 0, 0};
        tgt_s[e] = valid ? g : -1;
    }
    __syncthreads();

    f32x4 acc[2][5];
    short8 Af[2];

    // ---- s=0: L0 (K=32) ----
#pragma unroll
    for (int mtl = 0; mtl < 2; ++mtl)
#pragma unroll
        for (int jj = 0; jj < 5; ++jj) acc[mtl][jj] = f32x4{0.f, 0.f, 0.f, 0.f};
#pragma unroll
    for (int mtl = 0; mtl < 2; ++mtl)
        Af[mtl] = *(const short8*)&act[((mg * 2 + mtl) * 16 + col) * SA + quad * 8];
#pragma unroll
    for (int jj = 0; jj < 5; ++jj)
#pragma unroll
        for (int mtl = 0; mtl < 2; ++mtl)
            acc[mtl][jj] = __builtin_amdgcn_mfma_f32_16x16x32_bf16(
                Af[mtl], Bwin[0][jj], acc[mtl][jj], 0, 0, 0);
    loadB(Wt, 3, ng, lane, Bwin[0]);       // refill slot 0 (s=3)
    __syncthreads();                        // A-reads done
    epilogue(act, Bp, 0, mg, ng, col, quad, acc);
    __syncthreads();                        // epilogue visible

    // ---- s=1..15: L1..L3 ----
#pragma unroll
    for (int s = 1; s <= 15; ++s) {
        const int l = 1 + (s - 1) / 5;
        const int ks = (s - 1) % 5;
        const int slot = s % 3;
        if (ks == 0) {
#pragma unroll
            for (int mtl = 0; mtl < 2; ++mtl)
#pragma unroll
                for (int jj = 0; jj < 5; ++jj) acc[mtl][jj] = f32x4{0.f, 0.f, 0.f, 0.f};
        }
#pragma unroll
        for (int mtl = 0; mtl < 2; ++mtl)
            Af[mtl] = *(const short8*)&act[((mg * 2 + mtl) * 16 + col) * SA
                                           + ks * 32 + quad * 8];
#pragma unroll
        for (int jj = 0; jj < 5; ++jj)
#pragma unroll
            for (int mtl = 0; mtl < 2; ++mtl)
                acc[mtl][jj] = __builtin_amdgcn_mfma_f32_16x16x32_bf16(
                    Af[mtl], Bwin[slot][jj], acc[mtl][jj], 0, 0, 0);
        if (s + 3 <= 20) loadB(Wt, s + 3, ng, lane, Bwin[slot]);
        if (ks == 4) {
            __syncthreads();                // all A-reads of layer l done
            epilogue(act, Bp, l, mg, ng, col, quad, acc);
            __syncthreads();                // epilogue visible
        }
    }

    // ---- s=16..20: L4 — one M-tile per wave (mt = 2mg+ng), full N=4 --------
    const int mt4 = mg * 2 + ng;
    f32x4 acc4[4];
#pragma unroll
    for (int jj = 0; jj < 4; ++jj) acc4[jj] = f32x4{0.f, 0.f, 0.f, 0.f};
#pragma unroll
    for (int s = 16; s <= 20; ++s) {
        const int ks = s - 16;
        const int slot = s % 3;
        const short8 A4 = *(const short8*)&act[(mt4 * 16 + col) * SA
                                               + ks * 32 + quad * 8];
#pragma unroll
        for (int jj = 0; jj < 4; ++jj)
            acc4[jj] = __builtin_amdgcn_mfma_f32_16x16x32_bf16(
                A4, Bwin[slot][jj], acc4[jj], 0, 0, 0);
        if (s + 3 <= 20) loadB(Wt, s + 3, ng, lane, Bwin[slot]);  // refill 19,20
    }

    // ---- scatter-add E into XCD-local Ep copy ----
#pragma unroll
    for (int jj = 0; jj < 4; ++jj) {
        const int n = jj * 16 + col;
        if (n < 50) {
            const float bb = Bp[4 * 160 + n];
#pragma unroll
            for (int r = 0; r < 4; ++r) {
                const int g = tgt_s[mt4 * 16 + quad * 4 + r];
                if (g >= 0) atomicAdd(&Epc[(size_t)g * 50 + n], acc4[jj][r] + bb);
            }
        }
    }
}

// ---------------- Node kernel: reduce copies + fO MLP (fp32 VALU) -----------
template<int DI, int DO, bool RELU>
__device__ __forceinline__ void mlp_layer_t(
    const float* __restrict__ W, const float* __restrict__ B,
    float (*in)[64], float (*out)[64], int tid)
{
    const int et = tid & 15;
    const int jt = tid >> 4;
    constexpr int NG = (DO + 15) / 16;

    float acc0[NG], acc1[NG], acc2[NG], acc3[NG];
#pragma unroll
    for (int g = 0; g < NG; ++g) {
        const int j = jt + 16 * g;
        const float bb = (j < DO) ? B[j] : 0.f;
        acc0[g] = bb; acc1[g] = bb; acc2[g] = bb; acc3[g] = bb;
    }
    for (int k = 0; k < DI; ++k) {
        const float4 a = *(const float4*)&in[k][et * 4];
#pragma unroll
        for (int g = 0; g < NG; ++g) {
            const int j = jt + 16 * g;
            const float wv = (j < DO) ? W[k * DO + j] : 0.f;
            acc0[g] = fmaf(a.x, wv, acc0[g]);
            acc1[g] = fmaf(a.y, wv, acc1[g]);
            acc2[g] = fmaf(a.z, wv, acc2[g]);
            acc3[g] = fmaf(a.w, wv, acc3[g]);
        }
    }
#pragma unroll
    for (int g = 0; g < NG; ++g) {
        const int j = jt + 16 * g;
        if (j < DO) {
            float4 v; v.x = acc0[g]; v.y = acc1[g]; v.z = acc2[g]; v.w = acc3[g];
            if (RELU) {
                v.x = fmaxf(v.x, 0.f); v.y = fmaxf(v.y, 0.f);
                v.z = fmaxf(v.z, 0.f); v.w = fmaxf(v.w, 0.f);
            }
            *(float4*)&out[j][et * 4] = v;
        }
    }
}

__global__ __launch_bounds__(256, 2) void node_kernel(
    const float* __restrict__ Ep, int ncopies, size_t copy_elems,
    const float* __restrict__ W0, const float* __restrict__ B0,
    const float* __restrict__ W1, const float* __restrict__ B1,
    float* __restrict__ P, int n_nodes)
{
    __shared__ float bufA[104][64];
    __shared__ float bufB[104][64];
    const int tid = threadIdx.x;
    const int n0  = blockIdx.x * 64;

    for (int idx = tid; idx < 64 * 50; idx += 256) {
        const int e = idx / 50;
        const int k = idx - e * 50;
        const int n = n0 + e;
        float s = 0.f;
        if (n < n_nodes) {
            const float* p = &Ep[(size_t)n * 50 + k];
            for (int c = 0; c < ncopies; ++c) s += p[(size_t)c * copy_elems];
        }
        bufA[k][e] = s;
    }
    __syncthreads();
    mlp_layer_t<50, 100, true >(W0, B0, bufA, bufB, tid); __syncthreads();
    mlp_layer_t<100, 4, false>(W1, B1, bufB, bufA, tid); __syncthreads();
    for (int idx = tid; idx < 64 * 4; idx += 256) {
        const int e = idx & 63;
        const int j = idx >> 6;
        const int n = n0 + e;
        if (n < n_nodes) P[(size_t)n * 4 + j] = bufA[j][e];
    }
}

// ------------------------------- launcher -----------------------------------
extern "C" void kernel_launch(void* const* d_in, const int* in_sizes, int n_in,
                              void* d_out, int out_size, void* d_ws, size_t ws_size,
                              hipStream_t stream)
{
    const float* t   = (const float*)d_in[0];
    const float* x   = (const float*)d_in[1];
    const float* Ofx = (const float*)d_in[2];
    const int*   src = (const int*)d_in[3];
    const int*   tgt = (const int*)d_in[4];
    const float* W0  = (const float*)d_in[5];  const float* B0 = (const float*)d_in[6];
    const float* W1  = (const float*)d_in[7];  const float* B1 = (const float*)d_in[8];
    const float* W2  = (const float*)d_in[9];  const float* B2 = (const float*)d_in[10];
    const float* W3  = (const float*)d_in[11]; const float* B3 = (const float*)d_in[12];
    const float* W4  = (const float*)d_in[13]; const float* B4 = (const float*)d_in[14];
    const float* OW0 = (const float*)d_in[15]; const float* OB0 = (const float*)d_in[16];
    const float* OW1 = (const float*)d_in[17]; const float* OB1 = (const float*)d_in[18];

    const int n_nodes = in_sizes[1] / 4;
    const int n_edges = in_sizes[3];

    u16*   Wt = (u16*)d_ws;                                  // 256000 B
    float* Bp = (float*)((char*)d_ws + WT_BYTES);            // 5 x 160 floats
    float* Ep = (float*)((char*)d_ws + WS_HDR);              // ncopies x [N,50] fp32

    const size_t copy_elems = (size_t)n_nodes * 50;
    const size_t avail = (ws_size > WS_HDR) ? ws_size - WS_HDR : 0;
    int ncopies = 1;                                          // power of two, <= 2
    while (ncopies * 2 <= 2 &&
           (size_t)(ncopies * 2) * copy_elems * sizeof(float) <= avail)
        ncopies *= 2;
    const int copy_mask = ncopies - 1;

    prep_all<<<dim3(32, 6), 256, 0, stream>>>(W0, W1, W2, W3, W4,
                                              B0, B1, B2, B3, B4, Wt, Bp);
    hipMemsetAsync(Ep, 0, (size_t)ncopies * copy_elems * sizeof(float), stream);

    edge_kernel<<<(n_edges + BLK_E - 1) / BLK_E, NTHR, 0, stream>>>(
        t, x, Ofx, src, tgt, Wt, Bp, Ep, n_edges, copy_mask, copy_elems);

    node_kernel<<<(n_nodes + 63) / 64, 256, 0, stream>>>(
        Ep, ncopies, copy_elems, OW0, OB0, OW1, OB1, (float*)d_out, n_nodes);
}

// Round 15
// 884.987 us; speedup vs baseline: 1.0963x; 1.0963x over previous
//
#include <hip/hip_runtime.h>
#include <hip/hip_bf16.h>

typedef unsigned short u16;
typedef __attribute__((ext_vector_type(8))) short short8;
typedef __attribute__((ext_vector_type(4))) float f32x4;

constexpr int SA     = 168;    // act row stride (bf16): 336 B
constexpr int BLK_E  = 64;     // edges per block
constexpr int NTHR   = 256;    // 4 waves = 2 M-groups x 2 N-groups (5/5 N-split)
constexpr int CHUNK  = 512;    // u16 elems per (ks,j) fragment chunk = 1 KB
constexpr int WSLOT  = 50 * CHUNK;              // 25600 elems per layer (5 ks x 10 j)
constexpr size_t WT_BYTES = 5ull * WSLOT * 2;   // 256000 B
constexpr size_t WS_HDR   = 262144;             // weights header

// slice schedule: s=0 -> (L0,ks0); s=1..15 -> L1..L3 (5 ks each); s=16..20 -> L4
constexpr int Ls (int s) { return s == 0 ? 0 : (s <= 15 ? 1 + (s - 1) / 5 : 4); }
constexpr int Kss(int s) { return s == 0 ? 0 : (s <= 15 ? (s - 1) % 5 : s - 16); }

__device__ __forceinline__ u16 f2bf(float f) {  // RNE (prep only)
    union { float f; unsigned u; } c; c.f = f;
    return (u16)((c.u + 0x7fffu + ((c.u >> 16) & 1u)) >> 16);
}
__device__ __forceinline__ unsigned pk_bf16(float a, float b) {  // v_cvt_pk_bf16_f32
    float2 f; f.x = a; f.y = b;
    __hip_bfloat162 h = __float22bfloat162_rn(f);
    return *(unsigned*)&h;
}

// act k'-storage (5/5 N-split):
//  tiles 0-3: k' = col*4 + j ; tiles 5-8: k' = 64 + col*4 + (j-5)
//  tile 4: k' = 128 + col    ; tile 9:  k' = 144 + col
__device__ __forceinline__ int kperm(int kp) {
    if (kp < 64)  return (kp & 3) * 16 + (kp >> 2);
    if (kp < 128) { const int m = kp - 64; return (5 + (m & 3)) * 16 + (m >> 2); }
    if (kp < 144) return 4 * 16 + (kp - 128);
    if (kp < 160) return 9 * 16 + (kp - 144);
    return 1 << 30;
}

// ---- prep: weights -> fragment-ordered chunks, BIAS FOLDED IN --------------
// Bias-neuron trick (exact): logical input k==150 (k==13 for L0) is a
// constant-1 column maintained by gather/epilogue; weight row 150 (13) holds
// the layer's bias. Weight column n==150 stays 0, so the pad outputs remain 0
// and the epilogue override (n=150 := 1) is the only act change.
__global__ void prep_all(const float* __restrict__ W0, const float* __restrict__ W1,
                         const float* __restrict__ W2, const float* __restrict__ W3,
                         const float* __restrict__ W4,
                         const float* __restrict__ B0, const float* __restrict__ B1,
                         const float* __restrict__ B2, const float* __restrict__ B3,
                         const float* __restrict__ B4,
                         u16* __restrict__ Wt)
{
    const int l = blockIdx.y;
    const float* W; const float* B; int DI, DO; bool perm;
    if      (l == 0) { W = W0; B = B0; DI = 13;  DO = 150; perm = false; }
    else if (l == 1) { W = W1; B = B1; DI = 150; DO = 150; perm = true;  }
    else if (l == 2) { W = W2; B = B2; DI = 150; DO = 150; perm = true;  }
    else if (l == 3) { W = W3; B = B3; DI = 150; DO = 150; perm = true;  }
    else             { W = W4; B = B4; DI = 150; DO = 50;  perm = true;  }
    const int kbias = (l == 0) ? 13 : 150;      // constant-1 input row
    u16* dst = Wt + (size_t)l * WSLOT;
    for (int idx = blockIdx.x * blockDim.x + threadIdx.x; idx < WSLOT;
         idx += gridDim.x * blockDim.x) {
        const int chunk = idx / CHUNK;            // = ks*10 + j
        const int within = idx - chunk * CHUNK;
        const int lane = within >> 3, e = within & 7;
        const int ks = chunk / 10, j = chunk - ks * 10;
        const int c = lane & 15, q = lane >> 4;
        const int n = j * 16 + c;
        const int kphys = ks * 32 + q * 8 + e;
        const int klog = perm ? kperm(kphys) : kphys;
        float v = 0.f;
        if (n < DO) {
            if (klog < DI)          v = W[klog * DO + n];
            else if (klog == kbias) v = B[n];     // folded bias row
        }
        dst[idx] = f2bf(v);
    }
}

// ---- B-load for slice s (plain global->VGPR, coalesced 1 KB chunks) --------
__device__ __forceinline__ void loadB(const u16* __restrict__ Wt, int s,
                                      int ng, int lane, short8 (&slot)[5])
{
    const int l = Ls(s), ks = Kss(s);
    const int jb = (l < 4) ? ng * 5 : 0;
    const int nt = (l < 4) ? 5 : 4;
    const u16* base = Wt + (size_t)l * WSLOT + (size_t)(ks * 10 + jb) * CHUNK + lane * 8;
#pragma unroll
    for (int jj = 0; jj < 5; ++jj)
        if (jj < nt) slot[jj] = *(const short8*)&base[jj * CHUNK];
}

// ---- epilogue: relu + packed bf16, k'-permuted in-place store --------------
// (bias already folded into the matmul; n==150 slot forced to 1.0)
__device__ __forceinline__ void epilogue(u16* act, int mg, int ng, int col, int quad,
                                         f32x4 (&acc)[2][5])
{
#pragma unroll
    for (int mtl = 0; mtl < 2; ++mtl)
#pragma unroll
        for (int r = 0; r < 4; ++r) {
            u16* row = &act[((mg * 2 + mtl) * 16 + quad * 4 + r) * SA];
            uint2 pk;
            pk.x = pk_bf16(fmaxf(acc[mtl][0][r], 0.f), fmaxf(acc[mtl][1][r], 0.f));
            pk.y = pk_bf16(fmaxf(acc[mtl][2][r], 0.f), fmaxf(acc[mtl][3][r], 0.f));
            *(uint2*)&row[ng * 64 + col * 4] = pk;                 // tiles 0-3 / 5-8
            u16 sv = (u16)pk_bf16(fmaxf(acc[mtl][4][r], 0.f), 0.f);
            if (ng == 1 && col == 6) sv = 0x3F80;                  // n=150 := 1.0
            row[128 + ng * 16 + col] = sv;                         // tile 4 / 9
        }
}

// ------------------------------- Edge kernel --------------------------------
// 4 waves = 2 M-groups (32 edges each) x 2 N-groups (5 N-tiles each).
// B: global->VGPR rolling 3-slice window. Bias folded into weights.
// Sync: 1 post-gather + 2 per layer boundary = 9 barriers.
__global__ __launch_bounds__(NTHR, 4) void edge_kernel(
    const float* __restrict__ t, const float* __restrict__ x, const float* __restrict__ Ofx,
    const int* __restrict__ src, const int* __restrict__ tgt,
    const u16* __restrict__ Wt,
    float* __restrict__ Ep, int n_edges, int copy_mask, size_t copy_elems)
{
    __shared__ __align__(16) u16 act[BLK_E * SA];      // 21504 B
    __shared__ int tgt_s[BLK_E];                       // 256 B

    const int tid  = threadIdx.x;
    const int lane = tid & 63;
    const int wv   = tid >> 6;
    const int mg   = wv >> 1;          // M-group: edges [mg*32, mg*32+32)
    const int ng   = wv & 1;           // N-group: tiles [ng*5, ng*5+5)
    const int col  = lane & 15;
    const int quad = lane >> 4;

    const int xcd = (int)(__builtin_amdgcn_s_getreg(6164) & 7u) & copy_mask;
    float* __restrict__ Epc = Ep + (size_t)xcd * copy_elems;

    short8 Bwin[3][5];
    loadB(Wt, 0, ng, lane, Bwin[0]);    // prologue: 3-deep lookahead
    loadB(Wt, 1, ng, lane, Bwin[1]);
    loadB(Wt, 2, ng, lane, Bwin[2]);

    // ---- gather R' (tid<64; k=13 is the constant-1 bias column for L0) ----
    if (tid < BLK_E) {
        const int e = tid;
        const long long ge = (long long)blockIdx.x * BLK_E + e;
        const bool valid = ge < n_edges;
        const int s = valid ? src[ge] : 0;
        const int g = valid ? tgt[ge] : 0;
        const float4 xs = valid ? *(const float4*)&x[(size_t)s * 4] : float4{0, 0, 0, 0};
        const float2 os = valid ? *(const float2*)&Ofx[(size_t)s * 2] : float2{0, 0};
        const float4 xg = valid ? *(const float4*)&x[(size_t)g * 4] : float4{0, 0, 0, 0};
        const float2 og = valid ? *(const float2*)&Ofx[(size_t)g * 2] : float2{0, 0};
        const float tv = valid ? t[0] : 0.f;
        uint4 w0, w1;
        w0.x = pk_bf16(xs.x, xs.y); w0.y = pk_bf16(xs.z, xs.w);
        w0.z = pk_bf16(os.x, os.y); w0.w = pk_bf16(xg.x, xg.y);
        w1.x = pk_bf16(xg.z, xg.w); w1.y = pk_bf16(og.x, og.y);
        w1.z = pk_bf16(tv, 1.0f);   w1.w = 0u;     // k=13 := 1 (bias neuron)
        u16* row = &act[e * SA];
        *(uint4*)&row[0]  = w0;
        *(uint4*)&row[8]  = w1;
        *(uint4*)&row[16] = uint4{0, 0, 0, 0};
        *(uint4*)&row[24] = uint4{0, 0, 0, 0};
        tgt_s[e] = valid ? g : -1;
    }
    __syncthreads();

    f32x4 acc[2][5];
    short8 Af[2];

    // ---- s=0: L0 (K=32) ----
#pragma unroll
    for (int mtl = 0; mtl < 2; ++mtl)
#pragma unroll
        for (int jj = 0; jj < 5; ++jj) acc[mtl][jj] = f32x4{0.f, 0.f, 0.f, 0.f};
#pragma unroll
    for (int mtl = 0; mtl < 2; ++mtl)
        Af[mtl] = *(const short8*)&act[((mg * 2 + mtl) * 16 + col) * SA + quad * 8];
#pragma unroll
    for (int jj = 0; jj < 5; ++jj)
#pragma unroll
        for (int mtl = 0; mtl < 2; ++mtl)
            acc[mtl][jj] = __builtin_amdgcn_mfma_f32_16x16x32_bf16(
                Af[mtl], Bwin[0][jj], acc[mtl][jj], 0, 0, 0);
    loadB(Wt, 3, ng, lane, Bwin[0]);       // refill slot 0 (s=3)
    __syncthreads();                        // A-reads done
    epilogue(act, mg, ng, col, quad, acc);
    __syncthreads();                        // epilogue visible

    // ---- s=1..15: L1..L3 ----
#pragma unroll
    for (int s = 1; s <= 15; ++s) {
        const int ks = (s - 1) % 5;
        const int slot = s % 3;
        if (ks == 0) {
#pragma unroll
            for (int mtl = 0; mtl < 2; ++mtl)
#pragma unroll
                for (int jj = 0; jj < 5; ++jj) acc[mtl][jj] = f32x4{0.f, 0.f, 0.f, 0.f};
        }
#pragma unroll
        for (int mtl = 0; mtl < 2; ++mtl)
            Af[mtl] = *(const short8*)&act[((mg * 2 + mtl) * 16 + col) * SA
                                           + ks * 32 + quad * 8];
#pragma unroll
        for (int jj = 0; jj < 5; ++jj)
#pragma unroll
            for (int mtl = 0; mtl < 2; ++mtl)
                acc[mtl][jj] = __builtin_amdgcn_mfma_f32_16x16x32_bf16(
                    Af[mtl], Bwin[slot][jj], acc[mtl][jj], 0, 0, 0);
        if (s + 3 <= 20) loadB(Wt, s + 3, ng, lane, Bwin[slot]);
        if (ks == 4) {
            __syncthreads();                // all A-reads of layer done
            epilogue(act, mg, ng, col, quad, acc);
            __syncthreads();                // epilogue visible
        }
    }

    // ---- s=16..20: L4 — one M-tile per wave (mt = 2mg+ng), full N=4 --------
    const int mt4 = mg * 2 + ng;
    f32x4 acc4[4];
#pragma unroll
    for (int jj = 0; jj < 4; ++jj) acc4[jj] = f32x4{0.f, 0.f, 0.f, 0.f};
#pragma unroll
    for (int s = 16; s <= 20; ++s) {
        const int ks = s - 16;
        const int slot = s % 3;
        const short8 A4 = *(const short8*)&act[(mt4 * 16 + col) * SA
                                               + ks * 32 + quad * 8];
#pragma unroll
        for (int jj = 0; jj < 4; ++jj)
            acc4[jj] = __builtin_amdgcn_mfma_f32_16x16x32_bf16(
                A4, Bwin[slot][jj], acc4[jj], 0, 0, 0);
        if (s + 3 <= 20) loadB(Wt, s + 3, ng, lane, Bwin[slot]);  // refill 19,20
    }

    // ---- scatter-add E into XCD-local Ep copy (bias already in acc) ----
#pragma unroll
    for (int jj = 0; jj < 4; ++jj) {
        const int n = jj * 16 + col;
        if (n < 50) {
#pragma unroll
            for (int r = 0; r < 4; ++r) {
                const int g = tgt_s[mt4 * 16 + quad * 4 + r];
                if (g >= 0) atomicAdd(&Epc[(size_t)g * 50 + n], acc4[jj][r]);
            }
        }
    }
}

// ---------------- Node kernel: reduce copies + fO MLP (fp32 VALU) -----------
template<int DI, int DO, bool RELU>
__device__ __forceinline__ void mlp_layer_t(
    const float* __restrict__ W, const float* __restrict__ B,
    float (*in)[64], float (*out)[64], int tid)
{
    const int et = tid & 15;
    const int jt = tid >> 4;
    constexpr int NG = (DO + 15) / 16;

    float acc0[NG], acc1[NG], acc2[NG], acc3[NG];
#pragma unroll
    for (int g = 0; g < NG; ++g) {
        const int j = jt + 16 * g;
        const float bb = (j < DO) ? B[j] : 0.f;
        acc0[g] = bb; acc1[g] = bb; acc2[g] = bb; acc3[g] = bb;
    }
    for (int k = 0; k < DI; ++k) {
        const float4 a = *(const float4*)&in[k][et * 4];
#pragma unroll
        for (int g = 0; g < NG; ++g) {
            const int j = jt + 16 * g;
            const float wv = (j < DO) ? W[k * DO + j] : 0.f;
            acc0[g] = fmaf(a.x, wv, acc0[g]);
            acc1[g] = fmaf(a.y, wv, acc1[g]);
            acc2[g] = fmaf(a.z, wv, acc2[g]);
            acc3[g] = fmaf(a.w, wv, acc3[g]);
        }
    }
#pragma unroll
    for (int g = 0; g < NG; ++g) {
        const int j = jt + 16 * g;
        if (j < DO) {
            float4 v; v.x = acc0[g]; v.y = acc1[g]; v.z = acc2[g]; v.w = acc3[g];
            if (RELU) {
                v.x = fmaxf(v.x, 0.f); v.y = fmaxf(v.y, 0.f);
                v.z = fmaxf(v.z, 0.f); v.w = fmaxf(v.w, 0.f);
            }
            *(float4*)&out[j][et * 4] = v;
        }
    }
}

__global__ __launch_bounds__(256, 2) void node_kernel(
    const float* __restrict__ Ep, int ncopies, size_t copy_elems,
    const float* __restrict__ W0, const float* __restrict__ B0,
    const float* __restrict__ W1, const float* __restrict__ B1,
    float* __restrict__ P, int n_nodes)
{
    __shared__ float bufA[104][64];
    __shared__ float bufB[104][64];
    const int tid = threadIdx.x;
    const int n0  = blockIdx.x * 64;

    for (int idx = tid; idx < 64 * 50; idx += 256) {
        const int e = idx / 50;
        const int k = idx - e * 50;
        const int n = n0 + e;
        float s = 0.f;
        if (n < n_nodes) {
            const float* p = &Ep[(size_t)n * 50 + k];
            for (int c = 0; c < ncopies; ++c) s += p[(size_t)c * copy_elems];
        }
        bufA[k][e] = s;
    }
    __syncthreads();
    mlp_layer_t<50, 100, true >(W0, B0, bufA, bufB, tid); __syncthreads();
    mlp_layer_t<100, 4, false>(W1, B1, bufB, bufA, tid); __syncthreads();
    for (int idx = tid; idx < 64 * 4; idx += 256) {
        const int e = idx & 63;
        const int j = idx >> 6;
        const int n = n0 + e;
        if (n < n_nodes) P[(size_t)n * 4 + j] = bufA[j][e];
    }
}

// ------------------------------- launcher -----------------------------------
extern "C" void kernel_launch(void* const* d_in, const int* in_sizes, int n_in,
                              void* d_out, int out_size, void* d_ws, size_t ws_size,
                              hipStream_t stream)
{
    const float* t   = (const float*)d_in[0];
    const float* x   = (const float*)d_in[1];
    const float* Ofx = (const float*)d_in[2];
    const int*   src = (const int*)d_in[3];
    const int*   tgt = (const int*)d_in[4];
    const float* W0  = (const float*)d_in[5];  const float* B0 = (const float*)d_in[6];
    const float* W1  = (const float*)d_in[7];  const float* B1 = (const float*)d_in[8];
    const float* W2  = (const float*)d_in[9];  const float* B2 = (const float*)d_in[10];
    const float* W3  = (const float*)d_in[11]; const float* B3 = (const float*)d_in[12];
    const float* W4  = (const float*)d_in[13]; const float* B4 = (const float*)d_in[14];
    const float* OW0 = (const float*)d_in[15]; const float* OB0 = (const float*)d_in[16];
    const float* OW1 = (const float*)d_in[17]; const float* OB1 = (const float*)d_in[18];

    const int n_nodes = in_sizes[1] / 4;
    const int n_edges = in_sizes[3];

    u16*   Wt = (u16*)d_ws;                                  // 256000 B
    float* Ep = (float*)((char*)d_ws + WS_HDR);              // ncopies x [N,50] fp32

    const size_t copy_elems = (size_t)n_nodes * 50;
    const size_t avail = (ws_size > WS_HDR) ? ws_size - WS_HDR : 0;
    int ncopies = 1;                                          // power of two, <= 2
    while (ncopies * 2 <= 2 &&
           (size_t)(ncopies * 2) * copy_elems * sizeof(float) <= avail)
        ncopies *= 2;
    const int copy_mask = ncopies - 1;

    prep_all<<<dim3(32, 5), 256, 0, stream>>>(W0, W1, W2, W3, W4,
                                              B0, B1, B2, B3, B4, Wt);
    hipMemsetAsync(Ep, 0, (size_t)ncopies * copy_elems * sizeof(float), stream);

    edge_kernel<<<(n_edges + BLK_E - 1) / BLK_E, NTHR, 0, stream>>>(
        t, x, Ofx, src, tgt, Wt, Ep, n_edges, copy_mask, copy_elems);

    node_kernel<<<(n_nodes + 63) / 64, 256, 0, stream>>>(
        Ep, ncopies, copy_elems, OW0, OB0, OW1, OB1, (float*)d_out, n_nodes);
}